// Round 3
// baseline (1168.661 us; speedup 1.0000x reference)
//
#include <hip/hip_runtime.h>
#include <hip/hip_bf16.h>

// CausalMultiHeadSelfAttention, MI355X gfx950.
// I/O dtype: fp32 (per reference setup_inputs/jnp.float32). Internal: bf16 MFMA.
// Pipeline:
//   0) conv_kernel grid.z=5: fp32 -> bf16 for x, Wq, Wk, Wv, Wo into ws.
//   1) gemm_kernel grid.z=3: Q/K/V = x @ W^T (bf16 MFMA 16x16x32, 128x128 tile,
//      global_load_lds staging). RoPE fused in Q/K epilogue (shfl_xor pair trick).
//      V stored transposed Vt[h][d][s] for contiguous PV B-fragments.
//   2) attn_kernel: 1 wave per (head, 16 q-rows), flash-style online softmax.
//   3) gemm_kernel mode 3: out = attn @ Wo^T -> d_out (fp32 store).
//
// Verified fragment layouts (cdna_hip_programming.md §3, m89/m91/m120):
//   A: A[m=lane&15][k=quad*8+j]   B: B[k=quad*8+j][n=lane&15]
//   C/D: col=lane&15, row=quad*4+reg

typedef __hip_bfloat16 bf16;
using s16x8 = __attribute__((ext_vector_type(8))) short;
using f32x4 = __attribute__((ext_vector_type(4))) float;

#define SEQ 4096
#define DMODEL 1024
#define NHEADS 16
#define DK 64
#define LOG2_THETA 13.287712379549449f  // log2(10000)

__device__ __forceinline__ void async16(const bf16* g, bf16* l) {
  __builtin_amdgcn_global_load_lds(
      (const __attribute__((address_space(1))) unsigned int*)g,
      (__attribute__((address_space(3))) unsigned int*)l, 16, 0, 0);
}

// fp32 -> bf16, 8 elems/thread. z=0: x (4M elems), z=1..4: weights (1M each).
__global__ __launch_bounds__(256)
void conv_kernel(const float* __restrict__ s0, const float* __restrict__ s1,
                 const float* __restrict__ s2, const float* __restrict__ s3,
                 const float* __restrict__ s4,
                 bf16* __restrict__ d0, bf16* __restrict__ d1,
                 bf16* __restrict__ d2, bf16* __restrict__ d3,
                 bf16* __restrict__ d4) {
  const int z = blockIdx.z;
  const float* s = (z == 0) ? s0 : (z == 1) ? s1 : (z == 2) ? s2 : (z == 3) ? s3 : s4;
  bf16* d = (z == 0) ? d0 : (z == 1) ? d1 : (z == 2) ? d2 : (z == 3) ? d3 : d4;
  const int n = (z == 0) ? SEQ * DMODEL : DMODEL * DMODEL;
  const int i = (blockIdx.x * 256 + threadIdx.x) * 8;
  if (i >= n) return;
  const float4 a = *(const float4*)(s + i);
  const float4 b = *(const float4*)(s + i + 4);
  union { bf16 h[8]; s16x8 v; } u;
  u.h[0] = __float2bfloat16(a.x); u.h[1] = __float2bfloat16(a.y);
  u.h[2] = __float2bfloat16(a.z); u.h[3] = __float2bfloat16(a.w);
  u.h[4] = __float2bfloat16(b.x); u.h[5] = __float2bfloat16(b.y);
  u.h[6] = __float2bfloat16(b.z); u.h[7] = __float2bfloat16(b.w);
  *(s16x8*)(d + i) = u.v;
}

// C = A[M=4096][K=1024] @ W^T, W row-major [N][K] (einsum 'bsi,oi->bso').
// mode 0: Q (rope, out [h][s][d])   mode 1: K (rope, [h][s][d])
// mode 2: V (no rope, out transposed [h][d][s])   mode 3: fp32 [s][n] store
__global__ __launch_bounds__(256)
void gemm_kernel(const bf16* __restrict__ A,
                 const bf16* __restrict__ W0, const bf16* __restrict__ W1,
                 const bf16* __restrict__ W2,
                 bf16* __restrict__ D0, bf16* __restrict__ D1,
                 bf16* __restrict__ D2, float* __restrict__ Df,
                 int mode_base) {
  const int mode = mode_base + (int)blockIdx.z;
  const bf16* __restrict__ W = (mode == 1) ? W1 : (mode == 2) ? W2 : W0;
  bf16* __restrict__ D = (mode == 1) ? D1 : (mode == 2) ? D2 : D0;

  const int tid  = threadIdx.x;
  const int lane = tid & 63;
  const int wave = tid >> 6;
  const int wm = wave >> 1, wn = wave & 1;
  const int quad = lane >> 4, l16 = lane & 15;
  const int m0 = blockIdx.x * 128;
  const int n0 = blockIdx.y * 128;

  __shared__ __align__(16) bf16 As[128 * 32];
  __shared__ __align__(16) bf16 Bs[128 * 32];

  f32x4 acc[4][4] = {};

  const int ldrow = lane >> 2;        // 0..15 within chunk
  const int ldcol = (lane & 3) * 8;   // bf16 col offset

  for (int k0 = 0; k0 < DMODEL; k0 += 32) {
#pragma unroll
    for (int c = 0; c < 2; ++c) {
      const int chunk = wave * 2 + c;          // 0..7, wave-uniform
      const int row = chunk * 16 + ldrow;
      async16(&A[(size_t)(m0 + row) * DMODEL + k0 + ldcol], &As[chunk * 512]);
      async16(&W[(size_t)(n0 + row) * DMODEL + k0 + ldcol], &Bs[chunk * 512]);
    }
    __syncthreads();  // drains vmcnt (global_load_lds) per compiler semantics

    s16x8 af[4], bfr[4];
#pragma unroll
    for (int i = 0; i < 4; ++i)
      af[i] = *(const s16x8*)&As[(wm * 64 + i * 16 + l16) * 32 + quad * 8];
#pragma unroll
    for (int j = 0; j < 4; ++j)
      bfr[j] = *(const s16x8*)&Bs[(wn * 64 + j * 16 + l16) * 32 + quad * 8];
#pragma unroll
    for (int i = 0; i < 4; ++i)
#pragma unroll
      for (int j = 0; j < 4; ++j)
        acc[i][j] = __builtin_amdgcn_mfma_f32_16x16x32_bf16(af[i], bfr[j],
                                                            acc[i][j], 0, 0, 0);
    __syncthreads();  // protect LDS before next iter's async stores
  }

  // ---- epilogue ----
  if (mode == 3) {  // fp32 store to output
#pragma unroll
    for (int i = 0; i < 4; ++i)
#pragma unroll
      for (int j = 0; j < 4; ++j) {
        const int col = n0 + wn * 64 + j * 16 + l16;
#pragma unroll
        for (int r = 0; r < 4; ++r) {
          const int srow = m0 + wm * 64 + i * 16 + quad * 4 + r;
          Df[(size_t)srow * DMODEL + col] = acc[i][j][r];
        }
      }
  } else if (mode == 2) {  // V -> Vt[h][d][s]
#pragma unroll
    for (int i = 0; i < 4; ++i)
#pragma unroll
      for (int j = 0; j < 4; ++j) {
        const int col = n0 + wn * 64 + j * 16 + l16;
        const int h = col >> 6, d = col & 63;
#pragma unroll
        for (int r = 0; r < 4; ++r) {
          const int srow = m0 + wm * 64 + i * 16 + quad * 4 + r;
          D[((size_t)h * DK + d) * SEQ + srow] = __float2bfloat16(acc[i][j][r]);
        }
      }
  } else {  // Q/K with RoPE -> [h][s][d]
#pragma unroll
    for (int j = 0; j < 4; ++j) {
      const int col = n0 + wn * 64 + j * 16 + l16;
      const int d = col & 63;
      const int h = col >> 6;
      const int p = d >> 1;
      const float invf = exp2f((float)p * (-2.0f / 64.0f) * LOG2_THETA);
#pragma unroll
      for (int i = 0; i < 4; ++i)
#pragma unroll
        for (int r = 0; r < 4; ++r) {
          const int srow = m0 + wm * 64 + i * 16 + quad * 4 + r;
          const float v = acc[i][j][r];
          const float partner = __shfl_xor(v, 1);  // col d^1, same row
          const float ang = (float)srow * invf;    // up to 4096 rad: need libm
          const float sn = sinf(ang);              // range reduction (v_sin
          const float cs = cosf(ang);              // domain is +-256 rev only)
          const float outv = (d & 1) ? fmaf(v, cs, partner * sn)
                                     : fmaf(v, cs, -partner * sn);
          D[((size_t)h * SEQ + srow) * DK + d] = __float2bfloat16(outv);
        }
    }
  }
}

// Flash attention: blockIdx.x = q-tile (16 rows), blockIdx.y = head. 64 threads.
__global__ __launch_bounds__(64)
void attn_kernel(const bf16* __restrict__ Q, const bf16* __restrict__ K,
                 const bf16* __restrict__ Vt, bf16* __restrict__ O) {
  const int lane = threadIdx.x;
  const int quad = lane >> 4, l16 = lane & 15;
  const int q0 = blockIdx.x * 16;
  const int h = blockIdx.y;
  const bf16* __restrict__ Qh = Q + (size_t)h * SEQ * DK;
  const bf16* __restrict__ Kh = K + (size_t)h * SEQ * DK;
  const bf16* __restrict__ Vh = Vt + (size_t)h * DK * SEQ;

  // Q fragments (A-operand): rows q0..q0+15, d split into two k=32 chunks
  s16x8 aq[2];
  aq[0] = *(const s16x8*)&Qh[(size_t)(q0 + l16) * DK + quad * 8];
  aq[1] = *(const s16x8*)&Qh[(size_t)(q0 + l16) * DK + 32 + quad * 8];

  float m_i[4], l_i[4];
  f32x4 oacc[4] = {};
#pragma unroll
  for (int r = 0; r < 4; ++r) { m_i[r] = -1e30f; l_i[r] = 0.0f; }

  __shared__ __align__(16) bf16 Pt[16 * 32];

  const int nb = (q0 + 15) / 32 + 1;  // causal block count, Bc=32
  for (int kb = 0; kb < nb; ++kb) {
    const int kv0 = kb * 32;
    f32x4 sc[2] = {};
#pragma unroll
    for (int hh = 0; hh < 2; ++hh) {
      const s16x8 bk0 =
          *(const s16x8*)&Kh[(size_t)(kv0 + hh * 16 + l16) * DK + quad * 8];
      const s16x8 bk1 =
          *(const s16x8*)&Kh[(size_t)(kv0 + hh * 16 + l16) * DK + 32 + quad * 8];
      sc[hh] = __builtin_amdgcn_mfma_f32_16x16x32_bf16(aq[0], bk0, sc[hh], 0, 0, 0);
      sc[hh] = __builtin_amdgcn_mfma_f32_16x16x32_bf16(aq[1], bk1, sc[hh], 0, 0, 0);
    }
    // scale + causal mask + online softmax (per row r; row lives in one quad)
#pragma unroll
    for (int r = 0; r < 4; ++r) {
      const int qrow = q0 + quad * 4 + r;
      float s0 = sc[0][r] * 0.125f;
      float s1 = sc[1][r] * 0.125f;
      if (kv0 + l16 > qrow) s0 = -1e30f;
      if (kv0 + 16 + l16 > qrow) s1 = -1e30f;
      float rmax = fmaxf(s0, s1);
#pragma unroll
      for (int off = 8; off; off >>= 1) rmax = fmaxf(rmax, __shfl_xor(rmax, off));
      const float mnew = fmaxf(m_i[r], rmax);
      const float alpha = __expf(m_i[r] - mnew);
      const float p0 = __expf(s0 - mnew);
      const float p1 = __expf(s1 - mnew);
      float rsum = p0 + p1;
#pragma unroll
      for (int off = 8; off; off >>= 1) rsum += __shfl_xor(rsum, off);
      l_i[r] = l_i[r] * alpha + rsum;
      m_i[r] = mnew;
#pragma unroll
      for (int ns = 0; ns < 4; ++ns) oacc[ns][r] *= alpha;
      // write P in [qrow][kv] layout for A-fragment re-read
      Pt[(quad * 4 + r) * 32 + l16] = __float2bfloat16(p0);
      Pt[(quad * 4 + r) * 32 + 16 + l16] = __float2bfloat16(p1);
    }
    __syncthreads();
    const s16x8 ap = *(const s16x8*)&Pt[l16 * 32 + quad * 8];  // A[m=q][k=kv]
#pragma unroll
    for (int ns = 0; ns < 4; ++ns) {
      const s16x8 bv =
          *(const s16x8*)&Vh[(size_t)(ns * 16 + l16) * SEQ + kv0 + quad * 8];
      oacc[ns] = __builtin_amdgcn_mfma_f32_16x16x32_bf16(ap, bv, oacc[ns], 0, 0, 0);
    }
    __syncthreads();
  }

  // epilogue: O[s][h*64+d]
#pragma unroll
  for (int ns = 0; ns < 4; ++ns)
#pragma unroll
    for (int r = 0; r < 4; ++r) {
      const int srow = q0 + quad * 4 + r;
      const float v = oacc[ns][r] / l_i[r];
      O[(size_t)srow * DMODEL + h * DK + ns * 16 + l16] = __float2bfloat16(v);
    }
}

extern "C" void kernel_launch(void* const* d_in, const int* in_sizes, int n_in,
                              void* d_out, int out_size, void* d_ws, size_t ws_size,
                              hipStream_t stream) {
  const float* x  = (const float*)d_in[0];
  const float* Wq = (const float*)d_in[1];
  const float* Wk = (const float*)d_in[2];
  const float* Wv = (const float*)d_in[3];
  const float* Wo = (const float*)d_in[4];
  float* out = (float*)d_out;

  bf16* ws = (bf16*)d_ws;
  bf16* xb   = ws;                                   // [4096][1024]
  bf16* Wqb  = xb  + (size_t)SEQ * DMODEL;           // [1024][1024]
  bf16* Wkb  = Wqb + (size_t)DMODEL * DMODEL;
  bf16* Wvb  = Wkb + (size_t)DMODEL * DMODEL;
  bf16* Wob  = Wvb + (size_t)DMODEL * DMODEL;
  bf16* Qb   = Wob + (size_t)DMODEL * DMODEL;        // [16][4096][64]
  bf16* Kb   = Qb  + (size_t)SEQ * DMODEL;           // [16][4096][64]
  bf16* Vtb  = Kb  + (size_t)SEQ * DMODEL;           // [16][64][4096]
  bf16* Attn = Vtb + (size_t)SEQ * DMODEL;           // [4096][1024]

  // fp32 -> bf16 conversions
  conv_kernel<<<dim3(SEQ * DMODEL / (256 * 8), 1, 5), 256, 0, stream>>>(
      x, Wq, Wk, Wv, Wo, xb, Wqb, Wkb, Wvb, Wob);
  // QKV projections (+RoPE, +V transpose), fused via grid.z
  gemm_kernel<<<dim3(SEQ / 128, DMODEL / 128, 3), 256, 0, stream>>>(
      xb, Wqb, Wkb, Wvb, Qb, Kb, Vtb, out, 0);
  // causal flash attention
  attn_kernel<<<dim3(SEQ / 16, NHEADS), 64, 0, stream>>>(Qb, Kb, Vtb, Attn);
  // output projection -> fp32 out
  gemm_kernel<<<dim3(SEQ / 128, DMODEL / 128, 1), 256, 0, stream>>>(
      Attn, Wob, Wob, Wob, Attn, Attn, Attn, out, 3);
}

// Round 4
// 608.100 us; speedup vs baseline: 1.9218x; 1.9218x over previous
//
#include <hip/hip_runtime.h>
#include <hip/hip_bf16.h>

// CausalMultiHeadSelfAttention, MI355X gfx950.
// I/O fp32, internal bf16 MFMA. R4: coalesced LDS-staged epilogues everywhere
// (R3 showed 69x write amplification from scalar 2B stores), attn Bc=64.

typedef __hip_bfloat16 bf16;
using s16x8 = __attribute__((ext_vector_type(8))) short;
using f32x4 = __attribute__((ext_vector_type(4))) float;

#define SEQ 4096
#define DMODEL 1024
#define NHEADS 16
#define DK 64
#define LOG2_THETA 13.287712379549449f  // log2(10000)

__device__ __forceinline__ void async16(const bf16* g, bf16* l) {
  __builtin_amdgcn_global_load_lds(
      (const __attribute__((address_space(1))) unsigned int*)g,
      (__attribute__((address_space(3))) unsigned int*)l, 16, 0, 0);
}

// fp32 -> bf16, 8 elems/thread. z=0: x (4M elems), z=1..4: weights (1M each).
__global__ __launch_bounds__(256)
void conv_kernel(const float* __restrict__ s0, const float* __restrict__ s1,
                 const float* __restrict__ s2, const float* __restrict__ s3,
                 const float* __restrict__ s4,
                 bf16* __restrict__ d0, bf16* __restrict__ d1,
                 bf16* __restrict__ d2, bf16* __restrict__ d3,
                 bf16* __restrict__ d4) {
  const int z = blockIdx.z;
  const float* s = (z == 0) ? s0 : (z == 1) ? s1 : (z == 2) ? s2 : (z == 3) ? s3 : s4;
  bf16* d = (z == 0) ? d0 : (z == 1) ? d1 : (z == 2) ? d2 : (z == 3) ? d3 : d4;
  const int n = (z == 0) ? SEQ * DMODEL : DMODEL * DMODEL;
  const int i = (blockIdx.x * 256 + threadIdx.x) * 8;
  if (i >= n) return;
  const float4 a = *(const float4*)(s + i);
  const float4 b = *(const float4*)(s + i + 4);
  union { bf16 h[8]; s16x8 v; } u;
  u.h[0] = __float2bfloat16(a.x); u.h[1] = __float2bfloat16(a.y);
  u.h[2] = __float2bfloat16(a.z); u.h[3] = __float2bfloat16(a.w);
  u.h[4] = __float2bfloat16(b.x); u.h[5] = __float2bfloat16(b.y);
  u.h[6] = __float2bfloat16(b.z); u.h[7] = __float2bfloat16(b.w);
  *(s16x8*)(d + i) = u.v;
}

// C = A[4096][1024] @ W^T.  mode 0/1: Q/K +RoPE -> [h][s][d].
// mode 2: V -> Vt[h][d][s].  mode 3: fp32 [s][n] -> Df.
__global__ __launch_bounds__(256)
void gemm_kernel(const bf16* __restrict__ A,
                 const bf16* __restrict__ W0, const bf16* __restrict__ W1,
                 const bf16* __restrict__ W2,
                 bf16* __restrict__ D0, bf16* __restrict__ D1,
                 bf16* __restrict__ D2, float* __restrict__ Df,
                 int mode_base) {
  const int mode = mode_base + (int)blockIdx.z;
  const bf16* __restrict__ W = (mode == 1) ? W1 : (mode == 2) ? W2 : W0;
  bf16* __restrict__ D = (mode == 1) ? D1 : (mode == 2) ? D2 : D0;

  const int tid  = threadIdx.x;
  const int lane = tid & 63;
  const int wave = tid >> 6;
  const int wm = wave >> 1, wn = wave & 1;
  const int quad = lane >> 4, l16 = lane & 15;
  const int m0 = blockIdx.x * 128;
  const int n0 = blockIdx.y * 128;

  __shared__ __align__(16) bf16 As[128 * 32];
  __shared__ __align__(16) bf16 Bs[128 * 32];
  __shared__ __align__(16) bf16 Es[4][64 * 64];  // per-wave epilogue staging

  f32x4 acc[4][4] = {};

  const int ldrow = lane >> 2;
  const int ldcol = (lane & 3) * 8;

  for (int k0 = 0; k0 < DMODEL; k0 += 32) {
#pragma unroll
    for (int c = 0; c < 2; ++c) {
      const int chunk = wave * 2 + c;
      const int row = chunk * 16 + ldrow;
      async16(&A[(size_t)(m0 + row) * DMODEL + k0 + ldcol], &As[chunk * 512]);
      async16(&W[(size_t)(n0 + row) * DMODEL + k0 + ldcol], &Bs[chunk * 512]);
    }
    __syncthreads();

    s16x8 af[4], bfr[4];
#pragma unroll
    for (int i = 0; i < 4; ++i)
      af[i] = *(const s16x8*)&As[(wm * 64 + i * 16 + l16) * 32 + quad * 8];
#pragma unroll
    for (int j = 0; j < 4; ++j)
      bfr[j] = *(const s16x8*)&Bs[(wn * 64 + j * 16 + l16) * 32 + quad * 8];
#pragma unroll
    for (int i = 0; i < 4; ++i)
#pragma unroll
      for (int j = 0; j < 4; ++j)
        acc[i][j] = __builtin_amdgcn_mfma_f32_16x16x32_bf16(af[i], bfr[j],
                                                            acc[i][j], 0, 0, 0);
    __syncthreads();
  }

  // ---- epilogue: stage into Es[wave], read back coalesced ----
  if (mode == 3) {  // fp32 out: direct stores (64B quad segments) are OK
#pragma unroll
    for (int i = 0; i < 4; ++i)
#pragma unroll
      for (int j = 0; j < 4; ++j) {
        const int col = n0 + wn * 64 + j * 16 + l16;
#pragma unroll
        for (int r = 0; r < 4; ++r) {
          const int srow = m0 + wm * 64 + i * 16 + quad * 4 + r;
          Df[(size_t)srow * DMODEL + col] = acc[i][j][r];
        }
      }
    return;
  }

  if (mode == 2) {  // transposed dump: Es[d_local][s_local]
#pragma unroll
    for (int i = 0; i < 4; ++i)
#pragma unroll
      for (int j = 0; j < 4; ++j)
#pragma unroll
        for (int r = 0; r < 4; ++r)
          Es[wave][(j * 16 + l16) * 64 + i * 16 + quad * 4 + r] =
              __float2bfloat16(acc[i][j][r]);
  } else {          // row-major dump: Es[s_local][d_local]
#pragma unroll
    for (int i = 0; i < 4; ++i)
#pragma unroll
      for (int j = 0; j < 4; ++j)
#pragma unroll
        for (int r = 0; r < 4; ++r)
          Es[wave][(i * 16 + quad * 4 + r) * 64 + j * 16 + l16] =
              __float2bfloat16(acc[i][j][r]);
  }
  __syncthreads();

  const int h = (n0 >> 6) + wn;         // wave's 64 cols = one head
  const int g  = lane >> 3;             // 0..7 row group
  const int c8 = (lane & 7) * 8;        // 0..56 col chunk (16B)

  if (mode == 2) {
    // lane: column d = t*8+g, 8 consecutive s at c8; 128B segments across lanes
#pragma unroll
    for (int t = 0; t < 8; ++t) {
      const int d = t * 8 + g;
      const s16x8 v = *(const s16x8*)&Es[wave][d * 64 + c8];
      *(s16x8*)&D[((size_t)h * DK + d) * SEQ + m0 + wm * 64 + c8] = v;
    }
  } else {
    // RoPE: pairs (c8+2k, c8+2k+1) in-lane; angle recurrence over t (rows +8)
    float sn[4], cs[4], s8[4], c8r[4], invf[4];
    const int srow0 = m0 + wm * 64 + g;
#pragma unroll
    for (int k = 0; k < 4; ++k) {
      const int p = (c8 >> 1) + k;
      invf[k] = exp2f((float)p * (-2.0f / 64.0f) * LOG2_THETA);
      sincosf((float)srow0 * invf[k], &sn[k], &cs[k]);
      sincosf(8.0f * invf[k], &s8[k], &c8r[k]);
    }
#pragma unroll
    for (int t = 0; t < 8; ++t) {
      const int rl = t * 8 + g;
      union { bf16 h[8]; s16x8 v; } u, o;
      u.v = *(const s16x8*)&Es[wave][rl * 64 + c8];
#pragma unroll
      for (int k = 0; k < 4; ++k) {
        const float x0 = __bfloat162float(u.h[2 * k]);
        const float x1 = __bfloat162float(u.h[2 * k + 1]);
        o.h[2 * k]     = __float2bfloat16(x0 * cs[k] - x1 * sn[k]);
        o.h[2 * k + 1] = __float2bfloat16(x1 * cs[k] + x0 * sn[k]);
        const float ns_ = sn[k] * c8r[k] + cs[k] * s8[k];   // advance row by 8
        cs[k] = cs[k] * c8r[k] - sn[k] * s8[k];
        sn[k] = ns_;
      }
      const int srow = m0 + wm * 64 + rl;
      *(s16x8*)&D[((size_t)h * SEQ + srow) * DK + c8] = o.v;
    }
  }
}

// Flash attention: blockIdx.x = q-tile (16 rows), blockIdx.y = head. 1 wave.
// Bc = 64 per iteration.
__global__ __launch_bounds__(64)
void attn_kernel(const bf16* __restrict__ Q, const bf16* __restrict__ K,
                 const bf16* __restrict__ Vt, bf16* __restrict__ O) {
  const int lane = threadIdx.x;
  const int quad = lane >> 4, l16 = lane & 15;
  const int q0 = blockIdx.x * 16;
  const int h = blockIdx.y;
  const bf16* __restrict__ Qh = Q + (size_t)h * SEQ * DK;
  const bf16* __restrict__ Kh = K + (size_t)h * SEQ * DK;
  const bf16* __restrict__ Vh = Vt + (size_t)h * DK * SEQ;

  s16x8 aq[2];
  aq[0] = *(const s16x8*)&Qh[(size_t)(q0 + l16) * DK + quad * 8];
  aq[1] = *(const s16x8*)&Qh[(size_t)(q0 + l16) * DK + 32 + quad * 8];

  float m_i[4], l_i[4];
  f32x4 oacc[4] = {};
#pragma unroll
  for (int r = 0; r < 4; ++r) { m_i[r] = -1e30f; l_i[r] = 0.0f; }

  __shared__ __align__(16) bf16 Pt[16 * 64];

  const int nb = q0 / 64 + 1;  // covers kv 0..q0+15 (q0 % 64 <= 48)
  for (int kb = 0; kb < nb; ++kb) {
    const int kv0 = kb * 64;
    f32x4 sc[4] = {};
#pragma unroll
    for (int hh = 0; hh < 4; ++hh) {
      const size_t row = (size_t)(kv0 + hh * 16 + l16) * DK;
      const s16x8 bk0 = *(const s16x8*)&Kh[row + quad * 8];
      const s16x8 bk1 = *(const s16x8*)&Kh[row + 32 + quad * 8];
      sc[hh] = __builtin_amdgcn_mfma_f32_16x16x32_bf16(aq[0], bk0, sc[hh], 0, 0, 0);
      sc[hh] = __builtin_amdgcn_mfma_f32_16x16x32_bf16(aq[1], bk1, sc[hh], 0, 0, 0);
    }
#pragma unroll
    for (int r = 0; r < 4; ++r) {
      const int qrow = q0 + quad * 4 + r;
      float s[4];
#pragma unroll
      for (int hh = 0; hh < 4; ++hh) {
        s[hh] = sc[hh][r] * 0.125f;
        if (kv0 + hh * 16 + l16 > qrow) s[hh] = -1e30f;
      }
      float rmax = fmaxf(fmaxf(s[0], s[1]), fmaxf(s[2], s[3]));
#pragma unroll
      for (int off = 8; off; off >>= 1) rmax = fmaxf(rmax, __shfl_xor(rmax, off));
      const float mnew = fmaxf(m_i[r], rmax);
      const float alpha = __expf(m_i[r] - mnew);
      float p[4], rsum = 0.0f;
#pragma unroll
      for (int hh = 0; hh < 4; ++hh) { p[hh] = __expf(s[hh] - mnew); rsum += p[hh]; }
#pragma unroll
      for (int off = 8; off; off >>= 1) rsum += __shfl_xor(rsum, off);
      l_i[r] = l_i[r] * alpha + rsum;
      m_i[r] = mnew;
#pragma unroll
      for (int ns = 0; ns < 4; ++ns) oacc[ns][r] *= alpha;
#pragma unroll
      for (int hh = 0; hh < 4; ++hh)
        Pt[(quad * 4 + r) * 64 + hh * 16 + l16] = __float2bfloat16(p[hh]);
    }
    __syncthreads();
    const s16x8 ap0 = *(const s16x8*)&Pt[l16 * 64 + quad * 8];
    const s16x8 ap1 = *(const s16x8*)&Pt[l16 * 64 + 32 + quad * 8];
#pragma unroll
    for (int ns = 0; ns < 4; ++ns) {
      const size_t vrow = (size_t)(ns * 16 + l16) * SEQ + kv0;
      const s16x8 bv0 = *(const s16x8*)&Vh[vrow + quad * 8];
      const s16x8 bv1 = *(const s16x8*)&Vh[vrow + 32 + quad * 8];
      oacc[ns] = __builtin_amdgcn_mfma_f32_16x16x32_bf16(ap0, bv0, oacc[ns], 0, 0, 0);
      oacc[ns] = __builtin_amdgcn_mfma_f32_16x16x32_bf16(ap1, bv1, oacc[ns], 0, 0, 0);
    }
    __syncthreads();
  }

  // coalesced O store via Pt staging (16 rows x 64 cols bf16)
#pragma unroll
  for (int ns = 0; ns < 4; ++ns)
#pragma unroll
    for (int r = 0; r < 4; ++r)
      Pt[(quad * 4 + r) * 64 + ns * 16 + l16] =
          __float2bfloat16(oacc[ns][r] / l_i[r]);
  __syncthreads();
  const int g = lane >> 3, c8 = (lane & 7) * 8;
#pragma unroll
  for (int t = 0; t < 2; ++t) {
    const int row = t * 8 + g;
    const s16x8 v = *(const s16x8*)&Pt[row * 64 + c8];
    *(s16x8*)&O[(size_t)(q0 + row) * DMODEL + h * DK + c8] = v;
  }
}

extern "C" void kernel_launch(void* const* d_in, const int* in_sizes, int n_in,
                              void* d_out, int out_size, void* d_ws, size_t ws_size,
                              hipStream_t stream) {
  const float* x  = (const float*)d_in[0];
  const float* Wq = (const float*)d_in[1];
  const float* Wk = (const float*)d_in[2];
  const float* Wv = (const float*)d_in[3];
  const float* Wo = (const float*)d_in[4];
  float* out = (float*)d_out;

  bf16* ws = (bf16*)d_ws;
  bf16* xb   = ws;
  bf16* Wqb  = xb  + (size_t)SEQ * DMODEL;
  bf16* Wkb  = Wqb + (size_t)DMODEL * DMODEL;
  bf16* Wvb  = Wkb + (size_t)DMODEL * DMODEL;
  bf16* Wob  = Wvb + (size_t)DMODEL * DMODEL;
  bf16* Qb   = Wob + (size_t)DMODEL * DMODEL;
  bf16* Kb   = Qb  + (size_t)SEQ * DMODEL;
  bf16* Vtb  = Kb  + (size_t)SEQ * DMODEL;
  bf16* Attn = Vtb + (size_t)SEQ * DMODEL;

  conv_kernel<<<dim3(SEQ * DMODEL / (256 * 8), 1, 5), 256, 0, stream>>>(
      x, Wq, Wk, Wv, Wo, xb, Wqb, Wkb, Wvb, Wob);
  gemm_kernel<<<dim3(SEQ / 128, DMODEL / 128, 3), 256, 0, stream>>>(
      xb, Wqb, Wkb, Wvb, Qb, Kb, Vtb, out, 0);
  attn_kernel<<<dim3(SEQ / 16, NHEADS), 64, 0, stream>>>(Qb, Kb, Vtb, Attn);
  gemm_kernel<<<dim3(SEQ / 128, DMODEL / 128, 1), 256, 0, stream>>>(
      Attn, Wob, Wob, Wob, Attn, Attn, Attn, out, 3);
}

// Round 5
// 603.776 us; speedup vs baseline: 1.9356x; 1.0072x over previous
//
#include <hip/hip_runtime.h>
#include <hip/hip_bf16.h>

// CausalMultiHeadSelfAttention, MI355X gfx950.
// I/O fp32, internal bf16 MFMA.
// R5: attention latency attack — vectorized softmax reductions (serial depth
// 32 shfl steps -> 8), V-loads hoisted above softmax, longest-first block
// order, mask only on last KV block, launch_bounds(64,4) for 4 waves/SIMD.

typedef __hip_bfloat16 bf16;
using s16x8 = __attribute__((ext_vector_type(8))) short;
using f32x4 = __attribute__((ext_vector_type(4))) float;

#define SEQ 4096
#define DMODEL 1024
#define NHEADS 16
#define DK 64
#define LOG2_THETA 13.287712379549449f  // log2(10000)

__device__ __forceinline__ void async16(const bf16* g, bf16* l) {
  __builtin_amdgcn_global_load_lds(
      (const __attribute__((address_space(1))) unsigned int*)g,
      (__attribute__((address_space(3))) unsigned int*)l, 16, 0, 0);
}

// fp32 -> bf16, 8 elems/thread. z=0: x (4M elems), z=1..4: weights (1M each).
__global__ __launch_bounds__(256)
void conv_kernel(const float* __restrict__ s0, const float* __restrict__ s1,
                 const float* __restrict__ s2, const float* __restrict__ s3,
                 const float* __restrict__ s4,
                 bf16* __restrict__ d0, bf16* __restrict__ d1,
                 bf16* __restrict__ d2, bf16* __restrict__ d3,
                 bf16* __restrict__ d4) {
  const int z = blockIdx.z;
  const float* s = (z == 0) ? s0 : (z == 1) ? s1 : (z == 2) ? s2 : (z == 3) ? s3 : s4;
  bf16* d = (z == 0) ? d0 : (z == 1) ? d1 : (z == 2) ? d2 : (z == 3) ? d3 : d4;
  const int n = (z == 0) ? SEQ * DMODEL : DMODEL * DMODEL;
  const int i = (blockIdx.x * 256 + threadIdx.x) * 8;
  if (i >= n) return;
  const float4 a = *(const float4*)(s + i);
  const float4 b = *(const float4*)(s + i + 4);
  union { bf16 h[8]; s16x8 v; } u;
  u.h[0] = __float2bfloat16(a.x); u.h[1] = __float2bfloat16(a.y);
  u.h[2] = __float2bfloat16(a.z); u.h[3] = __float2bfloat16(a.w);
  u.h[4] = __float2bfloat16(b.x); u.h[5] = __float2bfloat16(b.y);
  u.h[6] = __float2bfloat16(b.z); u.h[7] = __float2bfloat16(b.w);
  *(s16x8*)(d + i) = u.v;
}

// C = A[4096][1024] @ W^T.  mode 0/1: Q/K +RoPE -> [h][s][d].
// mode 2: V -> Vt[h][d][s].  mode 3: fp32 [s][n] -> Df.
__global__ __launch_bounds__(256)
void gemm_kernel(const bf16* __restrict__ A,
                 const bf16* __restrict__ W0, const bf16* __restrict__ W1,
                 const bf16* __restrict__ W2,
                 bf16* __restrict__ D0, bf16* __restrict__ D1,
                 bf16* __restrict__ D2, float* __restrict__ Df,
                 int mode_base) {
  const int mode = mode_base + (int)blockIdx.z;
  const bf16* __restrict__ W = (mode == 1) ? W1 : (mode == 2) ? W2 : W0;
  bf16* __restrict__ D = (mode == 1) ? D1 : (mode == 2) ? D2 : D0;

  const int tid  = threadIdx.x;
  const int lane = tid & 63;
  const int wave = tid >> 6;
  const int wm = wave >> 1, wn = wave & 1;
  const int quad = lane >> 4, l16 = lane & 15;
  const int m0 = blockIdx.x * 128;
  const int n0 = blockIdx.y * 128;

  __shared__ __align__(16) bf16 As[128 * 32];
  __shared__ __align__(16) bf16 Bs[128 * 32];
  __shared__ __align__(16) bf16 Es[4][64 * 64];  // per-wave epilogue staging

  f32x4 acc[4][4] = {};

  const int ldrow = lane >> 2;
  const int ldcol = (lane & 3) * 8;

  for (int k0 = 0; k0 < DMODEL; k0 += 32) {
#pragma unroll
    for (int c = 0; c < 2; ++c) {
      const int chunk = wave * 2 + c;
      const int row = chunk * 16 + ldrow;
      async16(&A[(size_t)(m0 + row) * DMODEL + k0 + ldcol], &As[chunk * 512]);
      async16(&W[(size_t)(n0 + row) * DMODEL + k0 + ldcol], &Bs[chunk * 512]);
    }
    __syncthreads();

    s16x8 af[4], bfr[4];
#pragma unroll
    for (int i = 0; i < 4; ++i)
      af[i] = *(const s16x8*)&As[(wm * 64 + i * 16 + l16) * 32 + quad * 8];
#pragma unroll
    for (int j = 0; j < 4; ++j)
      bfr[j] = *(const s16x8*)&Bs[(wn * 64 + j * 16 + l16) * 32 + quad * 8];
#pragma unroll
    for (int i = 0; i < 4; ++i)
#pragma unroll
      for (int j = 0; j < 4; ++j)
        acc[i][j] = __builtin_amdgcn_mfma_f32_16x16x32_bf16(af[i], bfr[j],
                                                            acc[i][j], 0, 0, 0);
    __syncthreads();
  }

  // ---- epilogue ----
  if (mode == 3) {  // fp32 out: direct stores (64B quad segments)
#pragma unroll
    for (int i = 0; i < 4; ++i)
#pragma unroll
      for (int j = 0; j < 4; ++j) {
        const int col = n0 + wn * 64 + j * 16 + l16;
#pragma unroll
        for (int r = 0; r < 4; ++r) {
          const int srow = m0 + wm * 64 + i * 16 + quad * 4 + r;
          Df[(size_t)srow * DMODEL + col] = acc[i][j][r];
        }
      }
    return;
  }

  if (mode == 2) {  // transposed dump: Es[d_local][s_local]
#pragma unroll
    for (int i = 0; i < 4; ++i)
#pragma unroll
      for (int j = 0; j < 4; ++j)
#pragma unroll
        for (int r = 0; r < 4; ++r)
          Es[wave][(j * 16 + l16) * 64 + i * 16 + quad * 4 + r] =
              __float2bfloat16(acc[i][j][r]);
  } else {          // row-major dump: Es[s_local][d_local]
#pragma unroll
    for (int i = 0; i < 4; ++i)
#pragma unroll
      for (int j = 0; j < 4; ++j)
#pragma unroll
        for (int r = 0; r < 4; ++r)
          Es[wave][(i * 16 + quad * 4 + r) * 64 + j * 16 + l16] =
              __float2bfloat16(acc[i][j][r]);
  }
  __syncthreads();

  const int h = (n0 >> 6) + wn;         // wave's 64 cols = one head
  const int g  = lane >> 3;             // 0..7 row group
  const int c8 = (lane & 7) * 8;        // 0..56 col chunk (16B)

  if (mode == 2) {
#pragma unroll
    for (int t = 0; t < 8; ++t) {
      const int d = t * 8 + g;
      const s16x8 v = *(const s16x8*)&Es[wave][d * 64 + c8];
      *(s16x8*)&D[((size_t)h * DK + d) * SEQ + m0 + wm * 64 + c8] = v;
    }
  } else {
    // RoPE: pairs (c8+2k, c8+2k+1) in-lane; angle recurrence over t (rows +8)
    float sn[4], cs[4], s8[4], c8r[4], invf[4];
    const int srow0 = m0 + wm * 64 + g;
#pragma unroll
    for (int k = 0; k < 4; ++k) {
      const int p = (c8 >> 1) + k;
      invf[k] = exp2f((float)p * (-2.0f / 64.0f) * LOG2_THETA);
      sincosf((float)srow0 * invf[k], &sn[k], &cs[k]);
      sincosf(8.0f * invf[k], &s8[k], &c8r[k]);
    }
#pragma unroll
    for (int t = 0; t < 8; ++t) {
      const int rl = t * 8 + g;
      union { bf16 h[8]; s16x8 v; } u, o;
      u.v = *(const s16x8*)&Es[wave][rl * 64 + c8];
#pragma unroll
      for (int k = 0; k < 4; ++k) {
        const float x0 = __bfloat162float(u.h[2 * k]);
        const float x1 = __bfloat162float(u.h[2 * k + 1]);
        o.h[2 * k]     = __float2bfloat16(x0 * cs[k] - x1 * sn[k]);
        o.h[2 * k + 1] = __float2bfloat16(x1 * cs[k] + x0 * sn[k]);
        const float ns_ = sn[k] * c8r[k] + cs[k] * s8[k];
        cs[k] = cs[k] * c8r[k] - sn[k] * s8[k];
        sn[k] = ns_;
      }
      const int srow = m0 + wm * 64 + rl;
      *(s16x8*)&D[((size_t)h * SEQ + srow) * DK + c8] = o.v;
    }
  }
}

// Flash attention. 1 wave per (head, 16 q-rows), Bc=64 per iteration.
// Longest-first dispatch; vectorized softmax; V hoisted above softmax.
__global__ __launch_bounds__(64, 4)
void attn_kernel(const bf16* __restrict__ Q, const bf16* __restrict__ K,
                 const bf16* __restrict__ Vt, bf16* __restrict__ O) {
  const int lane = threadIdx.x;
  const int quad = lane >> 4, l16 = lane & 15;
  const int q0 = (SEQ / 16 - 1 - (int)blockIdx.x) * 16;  // longest-first
  const int h = blockIdx.y;
  const bf16* __restrict__ Qh = Q + (size_t)h * SEQ * DK;
  const bf16* __restrict__ Kh = K + (size_t)h * SEQ * DK;
  const bf16* __restrict__ Vh = Vt + (size_t)h * DK * SEQ;

  const s16x8 aq0 = *(const s16x8*)&Qh[(size_t)(q0 + l16) * DK + quad * 8];
  const s16x8 aq1 = *(const s16x8*)&Qh[(size_t)(q0 + l16) * DK + 32 + quad * 8];

  f32x4 m4, l4;
#pragma unroll
  for (int r = 0; r < 4; ++r) { m4[r] = -1e30f; l4[r] = 0.0f; }
  f32x4 oacc[4] = {};

  __shared__ __align__(16) bf16 Pt[16 * 64];

  const int nb = q0 / 64 + 1;
  for (int kb = 0; kb < nb; ++kb) {
    const int kv0 = kb * 64;

    // K loads (gate QK) and V loads (hoisted: hidden behind QK+softmax)
    s16x8 bk[4][2], bv[4][2];
#pragma unroll
    for (int hh = 0; hh < 4; ++hh) {
      const size_t krow = (size_t)(kv0 + hh * 16 + l16) * DK;
      bk[hh][0] = *(const s16x8*)&Kh[krow + quad * 8];
      bk[hh][1] = *(const s16x8*)&Kh[krow + 32 + quad * 8];
      const size_t vrow = (size_t)(hh * 16 + l16) * SEQ + kv0;
      bv[hh][0] = *(const s16x8*)&Vh[vrow + quad * 8];
      bv[hh][1] = *(const s16x8*)&Vh[vrow + 32 + quad * 8];
    }

    f32x4 sc[4] = {};
#pragma unroll
    for (int hh = 0; hh < 4; ++hh) {
      sc[hh] = __builtin_amdgcn_mfma_f32_16x16x32_bf16(aq0, bk[hh][0], sc[hh], 0, 0, 0);
      sc[hh] = __builtin_amdgcn_mfma_f32_16x16x32_bf16(aq1, bk[hh][1], sc[hh], 0, 0, 0);
    }

    // scale (+ mask only on last block)
    f32x4 s4[4];
#pragma unroll
    for (int hh = 0; hh < 4; ++hh) s4[hh] = sc[hh] * 0.125f;
    if (kb == nb - 1) {
      const int base = q0 + quad * 4 - l16 - kv0;  // mask iff hh*16 > base + r
#pragma unroll
      for (int hh = 0; hh < 4; ++hh)
#pragma unroll
        for (int r = 0; r < 4; ++r)
          if (hh * 16 > base + r) s4[hh][r] = -1e30f;
    }

    // vectorized row-max reduce (4 independent chains per step)
    f32x4 rmax;
#pragma unroll
    for (int r = 0; r < 4; ++r)
      rmax[r] = fmaxf(fmaxf(s4[0][r], s4[1][r]), fmaxf(s4[2][r], s4[3][r]));
#pragma unroll
    for (int off = 8; off; off >>= 1) {
      f32x4 t;
#pragma unroll
      for (int r = 0; r < 4; ++r) t[r] = __shfl_xor(rmax[r], off);
#pragma unroll
      for (int r = 0; r < 4; ++r) rmax[r] = fmaxf(rmax[r], t[r]);
    }

    f32x4 mnew, alpha;
#pragma unroll
    for (int r = 0; r < 4; ++r) {
      mnew[r] = fmaxf(m4[r], rmax[r]);
      alpha[r] = __expf(m4[r] - mnew[r]);
    }
    f32x4 p[4];
#pragma unroll
    for (int hh = 0; hh < 4; ++hh)
#pragma unroll
      for (int r = 0; r < 4; ++r) p[hh][r] = __expf(s4[hh][r] - mnew[r]);
    f32x4 rsum = p[0] + p[1] + p[2] + p[3];
#pragma unroll
    for (int off = 8; off; off >>= 1) {
      f32x4 t;
#pragma unroll
      for (int r = 0; r < 4; ++r) t[r] = __shfl_xor(rsum[r], off);
      rsum += t;
    }
    l4 = l4 * alpha + rsum;
    m4 = mnew;
#pragma unroll
    for (int ns = 0; ns < 4; ++ns) oacc[ns] *= alpha;

    // P -> LDS (C layout -> A layout round trip)
#pragma unroll
    for (int hh = 0; hh < 4; ++hh)
#pragma unroll
      for (int r = 0; r < 4; ++r)
        Pt[(quad * 4 + r) * 64 + hh * 16 + l16] = __float2bfloat16(p[hh][r]);
    __syncthreads();
    const s16x8 ap0 = *(const s16x8*)&Pt[l16 * 64 + quad * 8];
    const s16x8 ap1 = *(const s16x8*)&Pt[l16 * 64 + 32 + quad * 8];
#pragma unroll
    for (int ns = 0; ns < 4; ++ns) {
      oacc[ns] = __builtin_amdgcn_mfma_f32_16x16x32_bf16(ap0, bv[ns][0], oacc[ns], 0, 0, 0);
      oacc[ns] = __builtin_amdgcn_mfma_f32_16x16x32_bf16(ap1, bv[ns][1], oacc[ns], 0, 0, 0);
    }
    __syncthreads();
  }

  // coalesced O store via Pt staging (16 rows x 64 cols bf16)
#pragma unroll
  for (int ns = 0; ns < 4; ++ns)
#pragma unroll
    for (int r = 0; r < 4; ++r)
      Pt[(quad * 4 + r) * 64 + ns * 16 + l16] =
          __float2bfloat16(oacc[ns][r] / l4[r]);
  __syncthreads();
  const int g = lane >> 3, c8 = (lane & 7) * 8;
#pragma unroll
  for (int t = 0; t < 2; ++t) {
    const int row = t * 8 + g;
    const s16x8 v = *(const s16x8*)&Pt[row * 64 + c8];
    *(s16x8*)&O[(size_t)(q0 + row) * DMODEL + h * DK + c8] = v;
  }
}

extern "C" void kernel_launch(void* const* d_in, const int* in_sizes, int n_in,
                              void* d_out, int out_size, void* d_ws, size_t ws_size,
                              hipStream_t stream) {
  const float* x  = (const float*)d_in[0];
  const float* Wq = (const float*)d_in[1];
  const float* Wk = (const float*)d_in[2];
  const float* Wv = (const float*)d_in[3];
  const float* Wo = (const float*)d_in[4];
  float* out = (float*)d_out;

  bf16* ws = (bf16*)d_ws;
  bf16* xb   = ws;
  bf16* Wqb  = xb  + (size_t)SEQ * DMODEL;
  bf16* Wkb  = Wqb + (size_t)DMODEL * DMODEL;
  bf16* Wvb  = Wkb + (size_t)DMODEL * DMODEL;
  bf16* Wob  = Wvb + (size_t)DMODEL * DMODEL;
  bf16* Qb   = Wob + (size_t)DMODEL * DMODEL;
  bf16* Kb   = Qb  + (size_t)SEQ * DMODEL;
  bf16* Vtb  = Kb  + (size_t)SEQ * DMODEL;
  bf16* Attn = Vtb + (size_t)SEQ * DMODEL;

  conv_kernel<<<dim3(SEQ * DMODEL / (256 * 8), 1, 5), 256, 0, stream>>>(
      x, Wq, Wk, Wv, Wo, xb, Wqb, Wkb, Wvb, Wob);
  gemm_kernel<<<dim3(SEQ / 128, DMODEL / 128, 3), 256, 0, stream>>>(
      xb, Wqb, Wkb, Wvb, Qb, Kb, Vtb, out, 0);
  attn_kernel<<<dim3(SEQ / 16, NHEADS), 64, 0, stream>>>(Qb, Kb, Vtb, Attn);
  gemm_kernel<<<dim3(SEQ / 128, DMODEL / 128, 1), 256, 0, stream>>>(
      Attn, Wob, Wob, Wob, Attn, Attn, Attn, out, 3);
}

// Round 6
// 443.108 us; speedup vs baseline: 2.6374x; 1.3626x over previous
//
#include <hip/hip_runtime.h>
#include <hip/hip_bf16.h>

// CausalMultiHeadSelfAttention, MI355X gfx950.
// I/O fp32, internal bf16 MFMA.
// R6: split-KV attention — 4 waves/block over one 16-row Q-tile, wave w takes
// KV blocks w, w+4, ... with private online-softmax state; LDS combine at end.
// Longest serial chain 64 -> 16 iters; barriers removed from hot loop
// (P round-trip is wave-private LDS). R5 post-mortem: 1-wave blocks left the
// causal tail latency-exposed (Occ 18%, VALU 10%) — structure, not per-iter
// cost, was the limit.

typedef __hip_bfloat16 bf16;
using s16x8 = __attribute__((ext_vector_type(8))) short;
using f32x4 = __attribute__((ext_vector_type(4))) float;

#define SEQ 4096
#define DMODEL 1024
#define NHEADS 16
#define DK 64
#define LOG2_THETA 13.287712379549449f  // log2(10000)

__device__ __forceinline__ void async16(const bf16* g, bf16* l) {
  __builtin_amdgcn_global_load_lds(
      (const __attribute__((address_space(1))) unsigned int*)g,
      (__attribute__((address_space(3))) unsigned int*)l, 16, 0, 0);
}

// fp32 -> bf16, 8 elems/thread. z=0: x (4M elems), z=1..4: weights (1M each).
__global__ __launch_bounds__(256)
void conv_kernel(const float* __restrict__ s0, const float* __restrict__ s1,
                 const float* __restrict__ s2, const float* __restrict__ s3,
                 const float* __restrict__ s4,
                 bf16* __restrict__ d0, bf16* __restrict__ d1,
                 bf16* __restrict__ d2, bf16* __restrict__ d3,
                 bf16* __restrict__ d4) {
  const int z = blockIdx.z;
  const float* s = (z == 0) ? s0 : (z == 1) ? s1 : (z == 2) ? s2 : (z == 3) ? s3 : s4;
  bf16* d = (z == 0) ? d0 : (z == 1) ? d1 : (z == 2) ? d2 : (z == 3) ? d3 : d4;
  const int n = (z == 0) ? SEQ * DMODEL : DMODEL * DMODEL;
  const int i = (blockIdx.x * 256 + threadIdx.x) * 8;
  if (i >= n) return;
  const float4 a = *(const float4*)(s + i);
  const float4 b = *(const float4*)(s + i + 4);
  union { bf16 h[8]; s16x8 v; } u;
  u.h[0] = __float2bfloat16(a.x); u.h[1] = __float2bfloat16(a.y);
  u.h[2] = __float2bfloat16(a.z); u.h[3] = __float2bfloat16(a.w);
  u.h[4] = __float2bfloat16(b.x); u.h[5] = __float2bfloat16(b.y);
  u.h[6] = __float2bfloat16(b.z); u.h[7] = __float2bfloat16(b.w);
  *(s16x8*)(d + i) = u.v;
}

// C = A[4096][1024] @ W^T.  mode 0/1: Q/K +RoPE -> [h][s][d].
// mode 2: V -> Vt[h][d][s].  mode 3: fp32 [s][n] -> Df.
__global__ __launch_bounds__(256)
void gemm_kernel(const bf16* __restrict__ A,
                 const bf16* __restrict__ W0, const bf16* __restrict__ W1,
                 const bf16* __restrict__ W2,
                 bf16* __restrict__ D0, bf16* __restrict__ D1,
                 bf16* __restrict__ D2, float* __restrict__ Df,
                 int mode_base) {
  const int mode = mode_base + (int)blockIdx.z;
  const bf16* __restrict__ W = (mode == 1) ? W1 : (mode == 2) ? W2 : W0;
  bf16* __restrict__ D = (mode == 1) ? D1 : (mode == 2) ? D2 : D0;

  const int tid  = threadIdx.x;
  const int lane = tid & 63;
  const int wave = tid >> 6;
  const int wm = wave >> 1, wn = wave & 1;
  const int quad = lane >> 4, l16 = lane & 15;
  const int m0 = blockIdx.x * 128;
  const int n0 = blockIdx.y * 128;

  __shared__ __align__(16) bf16 As[128 * 32];
  __shared__ __align__(16) bf16 Bs[128 * 32];
  __shared__ __align__(16) bf16 Es[4][64 * 64];  // per-wave epilogue staging

  f32x4 acc[4][4] = {};

  const int ldrow = lane >> 2;
  const int ldcol = (lane & 3) * 8;

  for (int k0 = 0; k0 < DMODEL; k0 += 32) {
#pragma unroll
    for (int c = 0; c < 2; ++c) {
      const int chunk = wave * 2 + c;
      const int row = chunk * 16 + ldrow;
      async16(&A[(size_t)(m0 + row) * DMODEL + k0 + ldcol], &As[chunk * 512]);
      async16(&W[(size_t)(n0 + row) * DMODEL + k0 + ldcol], &Bs[chunk * 512]);
    }
    __syncthreads();

    s16x8 af[4], bfr[4];
#pragma unroll
    for (int i = 0; i < 4; ++i)
      af[i] = *(const s16x8*)&As[(wm * 64 + i * 16 + l16) * 32 + quad * 8];
#pragma unroll
    for (int j = 0; j < 4; ++j)
      bfr[j] = *(const s16x8*)&Bs[(wn * 64 + j * 16 + l16) * 32 + quad * 8];
#pragma unroll
    for (int i = 0; i < 4; ++i)
#pragma unroll
      for (int j = 0; j < 4; ++j)
        acc[i][j] = __builtin_amdgcn_mfma_f32_16x16x32_bf16(af[i], bfr[j],
                                                            acc[i][j], 0, 0, 0);
    __syncthreads();
  }

  // ---- epilogue ----
  if (mode == 3) {  // fp32 out: direct stores (64B quad segments)
#pragma unroll
    for (int i = 0; i < 4; ++i)
#pragma unroll
      for (int j = 0; j < 4; ++j) {
        const int col = n0 + wn * 64 + j * 16 + l16;
#pragma unroll
        for (int r = 0; r < 4; ++r) {
          const int srow = m0 + wm * 64 + i * 16 + quad * 4 + r;
          Df[(size_t)srow * DMODEL + col] = acc[i][j][r];
        }
      }
    return;
  }

  if (mode == 2) {  // transposed dump: Es[d_local][s_local]
#pragma unroll
    for (int i = 0; i < 4; ++i)
#pragma unroll
      for (int j = 0; j < 4; ++j)
#pragma unroll
        for (int r = 0; r < 4; ++r)
          Es[wave][(j * 16 + l16) * 64 + i * 16 + quad * 4 + r] =
              __float2bfloat16(acc[i][j][r]);
  } else {          // row-major dump: Es[s_local][d_local]
#pragma unroll
    for (int i = 0; i < 4; ++i)
#pragma unroll
      for (int j = 0; j < 4; ++j)
#pragma unroll
        for (int r = 0; r < 4; ++r)
          Es[wave][(i * 16 + quad * 4 + r) * 64 + j * 16 + l16] =
              __float2bfloat16(acc[i][j][r]);
  }
  __syncthreads();

  const int h = (n0 >> 6) + wn;         // wave's 64 cols = one head
  const int g  = lane >> 3;             // 0..7 row group
  const int c8 = (lane & 7) * 8;        // 0..56 col chunk (16B)

  if (mode == 2) {
#pragma unroll
    for (int t = 0; t < 8; ++t) {
      const int d = t * 8 + g;
      const s16x8 v = *(const s16x8*)&Es[wave][d * 64 + c8];
      *(s16x8*)&D[((size_t)h * DK + d) * SEQ + m0 + wm * 64 + c8] = v;
    }
  } else {
    // RoPE: pairs (c8+2k, c8+2k+1) in-lane; angle recurrence over t (rows +8)
    float sn[4], cs[4], s8[4], c8r[4], invf[4];
    const int srow0 = m0 + wm * 64 + g;
#pragma unroll
    for (int k = 0; k < 4; ++k) {
      const int p = (c8 >> 1) + k;
      invf[k] = exp2f((float)p * (-2.0f / 64.0f) * LOG2_THETA);
      sincosf((float)srow0 * invf[k], &sn[k], &cs[k]);
      sincosf(8.0f * invf[k], &s8[k], &c8r[k]);
    }
#pragma unroll
    for (int t = 0; t < 8; ++t) {
      const int rl = t * 8 + g;
      union { bf16 h[8]; s16x8 v; } u, o;
      u.v = *(const s16x8*)&Es[wave][rl * 64 + c8];
#pragma unroll
      for (int k = 0; k < 4; ++k) {
        const float x0 = __bfloat162float(u.h[2 * k]);
        const float x1 = __bfloat162float(u.h[2 * k + 1]);
        o.h[2 * k]     = __float2bfloat16(x0 * cs[k] - x1 * sn[k]);
        o.h[2 * k + 1] = __float2bfloat16(x1 * cs[k] + x0 * sn[k]);
        const float ns_ = sn[k] * c8r[k] + cs[k] * s8[k];
        cs[k] = cs[k] * c8r[k] - sn[k] * s8[k];
        sn[k] = ns_;
      }
      const int srow = m0 + wm * 64 + rl;
      *(s16x8*)&D[((size_t)h * SEQ + srow) * DK + c8] = o.v;
    }
  }
}

// Split-KV flash attention. Block = 4 waves over one (head, 16-row Q-tile).
// Wave w handles KV blocks kb = w, w+4, ... (Bc=64) with private (m,l,O);
// LDS combine at the end. No barriers in the hot loop (Pt is wave-private).
__global__ __launch_bounds__(256, 4)
void attn_kernel(const bf16* __restrict__ Q, const bf16* __restrict__ K,
                 const bf16* __restrict__ Vt, bf16* __restrict__ O) {
  const int tid  = threadIdx.x;
  const int lane = tid & 63;
  const int wave = tid >> 6;
  const int quad = lane >> 4, l16 = lane & 15;
  const int q0 = (SEQ / 16 - 1 - (int)blockIdx.x) * 16;  // longest-first
  const int h = blockIdx.y;
  const bf16* __restrict__ Qh = Q + (size_t)h * SEQ * DK;
  const bf16* __restrict__ Kh = K + (size_t)h * SEQ * DK;
  const bf16* __restrict__ Vh = Vt + (size_t)h * DK * SEQ;

  // 16 KB: fp32 combine buffer; during the loop, wave w uses the first 2 KB
  // of Osh[w] as its private bf16 P-transpose buffer (phases don't overlap).
  __shared__ __align__(16) float Osh[4][16][64];
  __shared__ float Mw[4][16], Lw[4][16];
  bf16* __restrict__ Ptw = (bf16*)&Osh[wave][0][0];

  const s16x8 aq0 = *(const s16x8*)&Qh[(size_t)(q0 + l16) * DK + quad * 8];
  const s16x8 aq1 = *(const s16x8*)&Qh[(size_t)(q0 + l16) * DK + 32 + quad * 8];

  f32x4 m4, l4;
#pragma unroll
  for (int r = 0; r < 4; ++r) { m4[r] = -1e30f; l4[r] = 0.0f; }
  f32x4 oacc[4] = {};

  const int nbtot = q0 / 64 + 1;
  for (int kb = wave; kb < nbtot; kb += 4) {
    const int kv0 = kb * 64;

    s16x8 bk[4][2], bv[4][2];
#pragma unroll
    for (int hh = 0; hh < 4; ++hh) {
      const size_t krow = (size_t)(kv0 + hh * 16 + l16) * DK;
      bk[hh][0] = *(const s16x8*)&Kh[krow + quad * 8];
      bk[hh][1] = *(const s16x8*)&Kh[krow + 32 + quad * 8];
      const size_t vrow = (size_t)(hh * 16 + l16) * SEQ + kv0;
      bv[hh][0] = *(const s16x8*)&Vh[vrow + quad * 8];
      bv[hh][1] = *(const s16x8*)&Vh[vrow + 32 + quad * 8];
    }

    f32x4 sc[4] = {};
#pragma unroll
    for (int hh = 0; hh < 4; ++hh) {
      sc[hh] = __builtin_amdgcn_mfma_f32_16x16x32_bf16(aq0, bk[hh][0], sc[hh], 0, 0, 0);
      sc[hh] = __builtin_amdgcn_mfma_f32_16x16x32_bf16(aq1, bk[hh][1], sc[hh], 0, 0, 0);
    }

    f32x4 s4[4];
#pragma unroll
    for (int hh = 0; hh < 4; ++hh) s4[hh] = sc[hh] * 0.125f;
    if (kb == nbtot - 1) {  // diagonal block: causal mask
      const int base = q0 + quad * 4 - l16 - kv0;
#pragma unroll
      for (int hh = 0; hh < 4; ++hh)
#pragma unroll
        for (int r = 0; r < 4; ++r)
          if (hh * 16 > base + r) s4[hh][r] = -1e30f;
    }

    // vectorized row-max reduce (within l16 group; 4 rows in flight)
    f32x4 rmax;
#pragma unroll
    for (int r = 0; r < 4; ++r)
      rmax[r] = fmaxf(fmaxf(s4[0][r], s4[1][r]), fmaxf(s4[2][r], s4[3][r]));
#pragma unroll
    for (int off = 8; off; off >>= 1) {
      f32x4 t;
#pragma unroll
      for (int r = 0; r < 4; ++r) t[r] = __shfl_xor(rmax[r], off);
#pragma unroll
      for (int r = 0; r < 4; ++r) rmax[r] = fmaxf(rmax[r], t[r]);
    }

    f32x4 mnew, alpha;
#pragma unroll
    for (int r = 0; r < 4; ++r) {
      mnew[r] = fmaxf(m4[r], rmax[r]);
      alpha[r] = __expf(m4[r] - mnew[r]);
    }
    f32x4 p[4];
#pragma unroll
    for (int hh = 0; hh < 4; ++hh)
#pragma unroll
      for (int r = 0; r < 4; ++r) p[hh][r] = __expf(s4[hh][r] - mnew[r]);
    f32x4 rsum = p[0] + p[1] + p[2] + p[3];
#pragma unroll
    for (int off = 8; off; off >>= 1) {
      f32x4 t;
#pragma unroll
      for (int r = 0; r < 4; ++r) t[r] = __shfl_xor(rsum[r], off);
      rsum += t;
    }
    l4 = l4 * alpha + rsum;
    m4 = mnew;
#pragma unroll
    for (int ns = 0; ns < 4; ++ns) oacc[ns] *= alpha;

    // wave-private P transpose (C layout -> A layout); no barrier needed
#pragma unroll
    for (int hh = 0; hh < 4; ++hh)
#pragma unroll
      for (int r = 0; r < 4; ++r)
        Ptw[(quad * 4 + r) * 64 + hh * 16 + l16] = __float2bfloat16(p[hh][r]);
    const s16x8 ap0 = *(const s16x8*)&Ptw[l16 * 64 + quad * 8];
    const s16x8 ap1 = *(const s16x8*)&Ptw[l16 * 64 + 32 + quad * 8];
#pragma unroll
    for (int ns = 0; ns < 4; ++ns) {
      oacc[ns] = __builtin_amdgcn_mfma_f32_16x16x32_bf16(ap0, bv[ns][0], oacc[ns], 0, 0, 0);
      oacc[ns] = __builtin_amdgcn_mfma_f32_16x16x32_bf16(ap1, bv[ns][1], oacc[ns], 0, 0, 0);
    }
  }

  // ---- combine: publish per-wave state, then reduce across waves ----
  if (l16 == 0) {
#pragma unroll
    for (int r = 0; r < 4; ++r) {
      Mw[wave][quad * 4 + r] = m4[r];
      Lw[wave][quad * 4 + r] = l4[r];
    }
  }
#pragma unroll
  for (int ns = 0; ns < 4; ++ns)
#pragma unroll
    for (int r = 0; r < 4; ++r)
      Osh[wave][quad * 4 + r][ns * 16 + l16] = oacc[ns][r];
  __syncthreads();

  // wave handles rows wave*4..+3; lane handles one column
#pragma unroll
  for (int rr = 0; rr < 4; ++rr) {
    const int row = wave * 4 + rr;
    const float M = fmaxf(fmaxf(Mw[0][row], Mw[1][row]),
                          fmaxf(Mw[2][row], Mw[3][row]));
    float L = 0.0f, o = 0.0f;
#pragma unroll
    for (int w2 = 0; w2 < 4; ++w2) {
      const float sc_ = __expf(Mw[w2][row] - M);
      L += Lw[w2][row] * sc_;
      o += Osh[w2][row][lane] * sc_;
    }
    O[(size_t)(q0 + row) * DMODEL + h * DK + lane] = __float2bfloat16(o / L);
  }
}

extern "C" void kernel_launch(void* const* d_in, const int* in_sizes, int n_in,
                              void* d_out, int out_size, void* d_ws, size_t ws_size,
                              hipStream_t stream) {
  const float* x  = (const float*)d_in[0];
  const float* Wq = (const float*)d_in[1];
  const float* Wk = (const float*)d_in[2];
  const float* Wv = (const float*)d_in[3];
  const float* Wo = (const float*)d_in[4];
  float* out = (float*)d_out;

  bf16* ws = (bf16*)d_ws;
  bf16* xb   = ws;
  bf16* Wqb  = xb  + (size_t)SEQ * DMODEL;
  bf16* Wkb  = Wqb + (size_t)DMODEL * DMODEL;
  bf16* Wvb  = Wkb + (size_t)DMODEL * DMODEL;
  bf16* Wob  = Wvb + (size_t)DMODEL * DMODEL;
  bf16* Qb   = Wob + (size_t)DMODEL * DMODEL;
  bf16* Kb   = Qb  + (size_t)SEQ * DMODEL;
  bf16* Vtb  = Kb  + (size_t)SEQ * DMODEL;
  bf16* Attn = Vtb + (size_t)SEQ * DMODEL;

  conv_kernel<<<dim3(SEQ * DMODEL / (256 * 8), 1, 5), 256, 0, stream>>>(
      x, Wq, Wk, Wv, Wo, xb, Wqb, Wkb, Wvb, Wob);
  gemm_kernel<<<dim3(SEQ / 128, DMODEL / 128, 3), 256, 0, stream>>>(
      xb, Wqb, Wkb, Wvb, Qb, Kb, Vtb, out, 0);
  attn_kernel<<<dim3(SEQ / 16, NHEADS), 256, 0, stream>>>(Qb, Kb, Vtb, Attn);
  gemm_kernel<<<dim3(SEQ / 128, DMODEL / 128, 1), 256, 0, stream>>>(
      Attn, Wob, Wob, Wob, Attn, Attn, Attn, out, 3);
}